// Round 1
// baseline (11843.694 us; speedup 1.0000x reference)
//
#include <hip/hip_runtime.h>
#include <hip/hip_bf16.h>

#define BB 64
#define SS 512
#define HH 1024
#define G4 4096

using bf8_t = __attribute__((ext_vector_type(8))) short;   // 8 bf16 (4 VGPRs)
using f32x4 = __attribute__((ext_vector_type(4))) float;   // 4 fp32 acc

__device__ inline ushort f2bf(float f) {
  __hip_bfloat16 h = __float2bfloat16(f);
  return *reinterpret_cast<ushort*>(&h);
}
__device__ inline float bf2f(ushort u) {
  unsigned v = ((unsigned)u) << 16;
  return __uint_as_float(v);
}

// fp32 [R][C] -> bf16 [C][R]
__global__ __launch_bounds__(256) void k_transpose_cast(
    const float* __restrict__ in, ushort* __restrict__ out, int R, int C) {
  __shared__ float tile[32][33];
  int c0 = blockIdx.x * 32, r0 = blockIdx.y * 32;
  int tx = threadIdx.x & 31, ty = threadIdx.x >> 5;  // 32 x 8
  for (int i = ty; i < 32; i += 8) {
    int r = r0 + i, c = c0 + tx;
    tile[i][tx] = (r < R && c < C) ? in[(size_t)r * C + c] : 0.f;
  }
  __syncthreads();
  for (int i = ty; i < 32; i += 8) {
    int c = c0 + i, r = r0 + tx;
    if (c < C && r < R) out[(size_t)c * R + r] = f2bf(tile[tx][i]);
  }
}

// Ae[row = t*64+b][k] = embed_tok[x[b][t]][k] + embed_pos[t][k], bf16
__global__ __launch_bounds__(256) void k_embed(
    const int* __restrict__ x, const float* __restrict__ etok,
    const float* __restrict__ epos, ushort* __restrict__ Ae) {
  int row = blockIdx.x;
  int t = row >> 6, b = row & 63;
  int tok = x[b * SS + t];
  const float4* tp = (const float4*)(etok + (size_t)tok * HH);
  const float4* pp = (const float4*)(epos + (size_t)t * HH);
  int i = threadIdx.x;  // 256 threads * float4 = 1024
  float4 a = tp[i], p = pp[i];
  ushort4 r = make_ushort4(f2bf(a.x + p.x), f2bf(a.y + p.y),
                           f2bf(a.z + p.z), f2bf(a.w + p.w));
  ((ushort4*)(Ae + (size_t)row * HH))[i] = r;
}

// C[m][n] (bf16) = A[m][k] @ Bt[n][k]^T + bias[n].  M,N mult of 128, K=1024.
__global__ __launch_bounds__(256) void k_gemm_xi(
    const ushort* __restrict__ Ag, const ushort* __restrict__ Bt,
    const float* __restrict__ bias, ushort* __restrict__ Cout, int N) {
  __shared__ alignas(16) ushort As[128 * 40];   // rows padded 32->40 shorts
  __shared__ alignas(16) ushort Bs[128 * 40];
  const int m0 = blockIdx.y * 128, n0 = blockIdx.x * 128;
  const int tid = threadIdx.x;
  const int srow = tid >> 1, shalf = tid & 1;   // stage: 2 thr/row, 16 shorts each
  const int w = tid >> 6, lane = tid & 63;
  const int wm = w >> 1, wn = w & 1;            // 2x2 waves, 64x64 each
  const int lr = lane & 15, kq = lane >> 4;
  f32x4 acc[4][4] = {};
  for (int k0 = 0; k0 < HH; k0 += 32) {
    const uint4* ga = (const uint4*)(Ag + (size_t)(m0 + srow) * HH + k0 + shalf * 16);
    const uint4* gb = (const uint4*)(Bt + (size_t)(n0 + srow) * HH + k0 + shalf * 16);
    uint4 va0 = ga[0], va1 = ga[1];
    uint4 vb0 = gb[0], vb1 = gb[1];
    __syncthreads();
    *(uint4*)&As[srow * 40 + shalf * 16]     = va0;
    *(uint4*)&As[srow * 40 + shalf * 16 + 8] = va1;
    *(uint4*)&Bs[srow * 40 + shalf * 16]     = vb0;
    *(uint4*)&Bs[srow * 40 + shalf * 16 + 8] = vb1;
    __syncthreads();
    bf8_t fa[4], fb[4];
#pragma unroll
    for (int i = 0; i < 4; ++i) {
      fa[i] = *(const bf8_t*)&As[(wm * 64 + i * 16 + lr) * 40 + kq * 8];
      fb[i] = *(const bf8_t*)&Bs[(wn * 64 + i * 16 + lr) * 40 + kq * 8];
    }
#pragma unroll
    for (int mi = 0; mi < 4; ++mi)
#pragma unroll
      for (int ni = 0; ni < 4; ++ni)
        acc[mi][ni] = __builtin_amdgcn_mfma_f32_16x16x32_bf16(fa[mi], fb[ni], acc[mi][ni], 0, 0, 0);
  }
#pragma unroll
  for (int mi = 0; mi < 4; ++mi) {
    int grow = m0 + wm * 64 + mi * 16 + kq * 4;
#pragma unroll
    for (int ni = 0; ni < 4; ++ni) {
      int gcol = n0 + wn * 64 + ni * 16 + lr;
      float bv = bias[gcol];
#pragma unroll
      for (int r = 0; r < 4; ++r)
        Cout[(size_t)(grow + r) * N + gcol] = f2bf(acc[mi][ni][r] + bv);
    }
  }
}

// One LSTM step. 64 WGs x 256 thr. WG owns 16 h-cols; wave g computes gate g.
__global__ __launch_bounds__(256) void k_step(
    const ushort* __restrict__ hprev,  // [64][1024] bf16
    const ushort* __restrict__ xit,    // [64][4096] bf16 (xi_t + bh folded)
    const ushort* __restrict__ Wh_t,   // [4096][1024] bf16
    float* __restrict__ cstate,        // [64][1024] fp32
    ushort* __restrict__ hout) {       // [64][1024] bf16
  __shared__ float zbuf[4][64][17];
  const int w = threadIdx.x >> 6;      // gate
  const int lane = threadIdx.x & 63;
  const int lr = lane & 15, kq = lane >> 4;
  const int n0 = blockIdx.x * 16;
  const int col = w * 1024 + n0 + lr;  // z column for this lane's B-frag
  const ushort* Wrow = Wh_t + (size_t)col * HH;
  f32x4 acc[4] = {};
  for (int k0 = 0; k0 < HH; k0 += 32) {
    bf8_t fb = *(const bf8_t*)(Wrow + k0 + kq * 8);
#pragma unroll
    for (int m = 0; m < 4; ++m) {
      bf8_t fa = *(const bf8_t*)(hprev + (size_t)(m * 16 + lr) * HH + k0 + kq * 8);
      acc[m] = __builtin_amdgcn_mfma_f32_16x16x32_bf16(fa, fb, acc[m], 0, 0, 0);
    }
  }
#pragma unroll
  for (int m = 0; m < 4; ++m)
#pragma unroll
    for (int r = 0; r < 4; ++r) {
      int b = m * 16 + kq * 4 + r;
      float xv = bf2f(xit[(size_t)b * G4 + col]);
      zbuf[w][b][lr] = acc[m][r] + xv;
    }
  __syncthreads();
  for (int idx = threadIdx.x; idx < 64 * 16; idx += 256) {
    int b = idx >> 4, n = idx & 15;
    float zi = zbuf[0][b][n], zf = zbuf[1][b][n];
    float zg = zbuf[2][b][n], zo = zbuf[3][b][n];
    float si = 1.f / (1.f + __expf(-zi));
    float sf = 1.f / (1.f + __expf(-zf));
    float so = 1.f / (1.f + __expf(-zo));
    float tg = tanhf(zg);
    int gc = n0 + n;
    float c = sf * cstate[b * HH + gc] + si * tg;
    cstate[b * HH + gc] = c;
    hout[(size_t)b * HH + gc] = f2bf(so * tanhf(c));
  }
}

// logits[b][t][a] = hs[t+1][b][:] . Wd_t[a][:] + bd[a]
__global__ __launch_bounds__(256) void k_logits(
    const ushort* __restrict__ hs1, const ushort* __restrict__ Wdt,
    const float* __restrict__ bd, float* __restrict__ out) {
  int gid = blockIdx.x * 256 + threadIdx.x;
  int a = gid & 15, row = gid >> 4;   // row = t*64+b
  int t = row >> 6, b = row & 63;
  const uint4* hp = (const uint4*)(hs1 + (size_t)row * HH);
  const uint4* wp = (const uint4*)(Wdt + (size_t)a * HH);
  float sum = 0.f;
#pragma unroll 4
  for (int i = 0; i < HH / 8; ++i) {
    uint4 hv = hp[i], wv = wp[i];
    const uint* hu = (const uint*)&hv;
    const uint* wu = (const uint*)&wv;
#pragma unroll
    for (int j = 0; j < 4; ++j) {
      sum += bf2f((ushort)(hu[j] & 0xffff)) * bf2f((ushort)(wu[j] & 0xffff));
      sum += bf2f((ushort)(hu[j] >> 16)) * bf2f((ushort)(wu[j] >> 16));
    }
  }
  out[32768 + ((size_t)b * SS + t) * 16 + a] = sum + bd[a];
}

extern "C" void kernel_launch(void* const* d_in, const int* in_sizes, int n_in,
                              void* d_out, int out_size, void* d_ws, size_t ws_size,
                              hipStream_t stream) {
  const int*   x    = (const int*)d_in[0];
  const float* etok = (const float*)d_in[4];
  const float* epos = (const float*)d_in[5];
  const float* Wi   = (const float*)d_in[6];
  const float* Wh   = (const float*)d_in[7];
  const float* bh   = (const float*)d_in[8];
  const float* Wd   = (const float*)d_in[9];
  const float* bd   = (const float*)d_in[10];

  char* ws = (char*)d_ws;
  size_t off = 0;
  ushort* Wi_t = (ushort*)(ws + off); off += (size_t)G4 * HH * 2;            // 8 MB
  ushort* Wh_t = (ushort*)(ws + off); off += (size_t)G4 * HH * 2;            // 8 MB
  ushort* Wd_t = (ushort*)(ws + off); off += 65536;                          // 32 KB (padded)
  ushort* Ae   = (ushort*)(ws + off); off += (size_t)BB * SS * HH * 2;       // 64 MB
  ushort* xi   = (ushort*)(ws + off); off += (size_t)BB * SS * G4 * 2;       // 256 MB
  ushort* hs   = (ushort*)(ws + off); off += (size_t)(SS + 1) * BB * HH * 2; // 64.1 MB
  float*  cst  = (float*)(ws + off);  off += (size_t)BB * HH * 4;            // 256 KB

  hipMemsetAsync(d_out, 0, (size_t)out_size * 4, stream);          // dummies = 0
  hipMemsetAsync(hs, 0, (size_t)BB * HH * 2, stream);              // h_0 = 0
  hipMemsetAsync(cst, 0, (size_t)BB * HH * 4, stream);             // c_0 = 0

  dim3 b256(256);
  k_transpose_cast<<<dim3(G4 / 32, HH / 32), b256, 0, stream>>>(Wi, Wi_t, HH, G4);
  k_transpose_cast<<<dim3(G4 / 32, HH / 32), b256, 0, stream>>>(Wh, Wh_t, HH, G4);
  k_transpose_cast<<<dim3(1, HH / 32), b256, 0, stream>>>(Wd, Wd_t, HH, 16);
  k_embed<<<BB * SS, b256, 0, stream>>>(x, etok, epos, Ae);
  k_gemm_xi<<<dim3(G4 / 128, BB * SS / 128), b256, 0, stream>>>(Ae, Wi_t, bh, xi, G4);
  for (int t = 0; t < SS; ++t) {
    k_step<<<64, b256, 0, stream>>>(hs + (size_t)t * BB * HH,
                                    xi + (size_t)t * BB * G4,
                                    Wh_t, cst,
                                    hs + (size_t)(t + 1) * BB * HH);
  }
  k_logits<<<BB * SS * 16 / 256, b256, 0, stream>>>(hs + (size_t)BB * HH, Wd_t, bd,
                                                    (float*)d_out);
}

// Round 2
// 11216.865 us; speedup vs baseline: 1.0559x; 1.0559x over previous
//
#include <hip/hip_runtime.h>
#include <hip/hip_bf16.h>

#define BB 64
#define SS 512
#define HH 1024
#define G4 4096

using bf8_t = __attribute__((ext_vector_type(8))) short;   // 8 bf16 (4 VGPRs)
using f32x4 = __attribute__((ext_vector_type(4))) float;   // 4 fp32 acc

__device__ inline ushort f2bf(float f) {
  __hip_bfloat16 h = __float2bfloat16(f);
  return *reinterpret_cast<ushort*>(&h);
}
__device__ inline float bf2f(ushort u) {
  unsigned v = ((unsigned)u) << 16;
  return __uint_as_float(v);
}

// fp32 [R][C] -> bf16 [C][R]
__global__ __launch_bounds__(256) void k_transpose_cast(
    const float* __restrict__ in, ushort* __restrict__ out, int R, int C) {
  __shared__ float tile[32][33];
  int c0 = blockIdx.x * 32, r0 = blockIdx.y * 32;
  int tx = threadIdx.x & 31, ty = threadIdx.x >> 5;  // 32 x 8
  for (int i = ty; i < 32; i += 8) {
    int r = r0 + i, c = c0 + tx;
    tile[i][tx] = (r < R && c < C) ? in[(size_t)r * C + c] : 0.f;
  }
  __syncthreads();
  for (int i = ty; i < 32; i += 8) {
    int c = c0 + i, r = r0 + tx;
    if (c < C && r < R) out[(size_t)c * R + r] = f2bf(tile[tx][i]);
  }
}

// Ae[row = t*64+b][k] = embed_tok[x[b][t]][k] + embed_pos[t][k], bf16
__global__ __launch_bounds__(256) void k_embed(
    const int* __restrict__ x, const float* __restrict__ etok,
    const float* __restrict__ epos, ushort* __restrict__ Ae) {
  int row = blockIdx.x;
  int t = row >> 6, b = row & 63;
  int tok = x[b * SS + t];
  const float4* tp = (const float4*)(etok + (size_t)tok * HH);
  const float4* pp = (const float4*)(epos + (size_t)t * HH);
  int i = threadIdx.x;  // 256 threads * float4 = 1024
  float4 a = tp[i], p = pp[i];
  ushort4 r = make_ushort4(f2bf(a.x + p.x), f2bf(a.y + p.y),
                           f2bf(a.z + p.z), f2bf(a.w + p.w));
  ((ushort4*)(Ae + (size_t)row * HH))[i] = r;
}

// C[m][n] (bf16) = A[m][k] @ Bt[n][k]^T + bias[n].  M,N mult of 128, K=1024.
__global__ __launch_bounds__(256) void k_gemm_xi(
    const ushort* __restrict__ Ag, const ushort* __restrict__ Bt,
    const float* __restrict__ bias, ushort* __restrict__ Cout, int N) {
  __shared__ alignas(16) ushort As[128 * 40];   // rows padded 32->40 shorts
  __shared__ alignas(16) ushort Bs[128 * 40];
  const int m0 = blockIdx.y * 128, n0 = blockIdx.x * 128;
  const int tid = threadIdx.x;
  const int srow = tid >> 1, shalf = tid & 1;   // stage: 2 thr/row, 16 shorts each
  const int w = tid >> 6, lane = tid & 63;
  const int wm = w >> 1, wn = w & 1;            // 2x2 waves, 64x64 each
  const int lr = lane & 15, kq = lane >> 4;
  f32x4 acc[4][4] = {};
  for (int k0 = 0; k0 < HH; k0 += 32) {
    const uint4* ga = (const uint4*)(Ag + (size_t)(m0 + srow) * HH + k0 + shalf * 16);
    const uint4* gb = (const uint4*)(Bt + (size_t)(n0 + srow) * HH + k0 + shalf * 16);
    uint4 va0 = ga[0], va1 = ga[1];
    uint4 vb0 = gb[0], vb1 = gb[1];
    __syncthreads();
    *(uint4*)&As[srow * 40 + shalf * 16]     = va0;
    *(uint4*)&As[srow * 40 + shalf * 16 + 8] = va1;
    *(uint4*)&Bs[srow * 40 + shalf * 16]     = vb0;
    *(uint4*)&Bs[srow * 40 + shalf * 16 + 8] = vb1;
    __syncthreads();
    bf8_t fa[4], fb[4];
#pragma unroll
    for (int i = 0; i < 4; ++i) {
      fa[i] = *(const bf8_t*)&As[(wm * 64 + i * 16 + lr) * 40 + kq * 8];
      fb[i] = *(const bf8_t*)&Bs[(wn * 64 + i * 16 + lr) * 40 + kq * 8];
    }
#pragma unroll
    for (int mi = 0; mi < 4; ++mi)
#pragma unroll
      for (int ni = 0; ni < 4; ++ni)
        acc[mi][ni] = __builtin_amdgcn_mfma_f32_16x16x32_bf16(fa[mi], fb[ni], acc[mi][ni], 0, 0, 0);
  }
#pragma unroll
  for (int mi = 0; mi < 4; ++mi) {
    int grow = m0 + wm * 64 + mi * 16 + kq * 4;
#pragma unroll
    for (int ni = 0; ni < 4; ++ni) {
      int gcol = n0 + wn * 64 + ni * 16 + lr;
      float bv = bias[gcol];
#pragma unroll
      for (int r = 0; r < 4; ++r)
        Cout[(size_t)(grow + r) * N + gcol] = f2bf(acc[mi][ni][r] + bv);
    }
  }
}

// Grid barrier among 64 co-resident WGs. Monotonic target avoids reset races.
__device__ inline void grid_bar(unsigned* bar, unsigned target) {
  __syncthreads();                 // all WG stores issued & waited (vmcnt)
  if (threadIdx.x == 0) {
    __threadfence();               // agent release: write back dirty L2
    __hip_atomic_fetch_add(bar, 1u, __ATOMIC_RELEASE, __HIP_MEMORY_SCOPE_AGENT);
    while (__hip_atomic_load(bar, __ATOMIC_RELAXED, __HIP_MEMORY_SCOPE_AGENT) < target)
      __builtin_amdgcn_s_sleep(2);
    __threadfence();               // agent acquire: invalidate L1/L2
  }
  __syncthreads();
}

// Persistent recurrence: 64 WGs x 256 thr, 1 WG/CU (LDS-limited).
// WG owns 16 h-cols; wave g computes gate g. Wh slice lives in LDS the whole
// time; c-state lives in registers; h goes through global + grid barrier.
__global__ __launch_bounds__(256) void k_recur(
    const ushort* __restrict__ Wh_t,   // [4096][1024] bf16
    const ushort* __restrict__ xi,     // [S*64][4096] bf16 (bh folded in)
    ushort* __restrict__ hs,           // [(S+1)*64][1024] bf16, hs[0]=0
    unsigned* __restrict__ bar) {
  // Wh slice: 64 rows (4 gates x 16 cols) x 1024 k, 16B-unit index
  // u = row*128 + (k16 ^ (row&7))  -> balanced 8 lanes per slot on ds_read_b128
  __shared__ alignas(16) ushort Wlds[64 * 1024];   // 128 KiB
  __shared__ float zbuf[4][64][17];                // 17 KiB
  const int wg = blockIdx.x;            // 0..63
  const int n0 = wg * 16;
  const int tid = threadIdx.x;

  // one-time stage of Wh slice (swizzled)
  for (int s = tid; s < 64 * 128; s += 256) {
    int row = s >> 7, k16 = s & 127;
    int g = row >> 4, j = row & 15;
    uint4 v = *(const uint4*)(Wh_t + (size_t)(g * 1024 + n0 + j) * HH + k16 * 8);
    *(uint4*)&Wlds[(row * 128 + (k16 ^ (row & 7))) * 8] = v;
  }
  __syncthreads();

  const int w = tid >> 6, lane = tid & 63;
  const int lr = lane & 15, kq = lane >> 4;
  const int tb = tid >> 2;              // batch row owned in epilogue
  const int tn = (tid & 3) * 4;         // first owned n (of 16)
  float cr[4] = {0.f, 0.f, 0.f, 0.f};   // c-state, persists across steps
  unsigned target = 0;

  for (int t = 0; t < SS; ++t) {
    const ushort* hprev = hs + (size_t)t * BB * HH;
    // prefetch this step's xi values for the epilogue (hides HBM latency)
    const ushort* xr = xi + ((size_t)t * 64 + tb) * G4 + n0 + tn;
    ushort4 xv[4];
#pragma unroll
    for (int g = 0; g < 4; ++g) xv[g] = *(const ushort4*)(xr + (size_t)g * 1024);

    f32x4 acc[4] = {};
#pragma unroll 4
    for (int k0 = 0; k0 < HH; k0 += 32) {
      bf8_t fb = *(const bf8_t*)&Wlds[((w * 16 + lr) * 128 +
                                       (((k0 >> 3) + kq) ^ (lr & 7))) * 8];
#pragma unroll
      for (int m = 0; m < 4; ++m) {
        bf8_t fa = *(const bf8_t*)(hprev + (size_t)(m * 16 + lr) * HH + k0 + kq * 8);
        acc[m] = __builtin_amdgcn_mfma_f32_16x16x32_bf16(fa, fb, acc[m], 0, 0, 0);
      }
    }
#pragma unroll
    for (int m = 0; m < 4; ++m)
#pragma unroll
      for (int r = 0; r < 4; ++r)
        zbuf[w][m * 16 + kq * 4 + r][lr] = acc[m][r];
    __syncthreads();

    // epilogue: thread owns (b=tb, n=tn..tn+3) across all 4 gates
    float z[4][4];
#pragma unroll
    for (int g = 0; g < 4; ++g) {
      const ushort* xg = (const ushort*)&xv[g];
#pragma unroll
      for (int r = 0; r < 4; ++r)
        z[g][r] = zbuf[g][tb][tn + r] + bf2f(xg[r]);
    }
    ushort4 ho;
#pragma unroll
    for (int r = 0; r < 4; ++r) {
      float si = 1.f / (1.f + __expf(-z[0][r]));
      float sf = 1.f / (1.f + __expf(-z[1][r]));
      float tg = tanhf(z[2][r]);
      float so = 1.f / (1.f + __expf(-z[3][r]));
      float c = sf * cr[r] + si * tg;
      cr[r] = c;
      ((ushort*)&ho)[r] = f2bf(so * tanhf(c));
    }
    *(ushort4*)(hs + (size_t)(t + 1) * BB * HH + (size_t)tb * HH + n0 + tn) = ho;

    target += 64;
    grid_bar(bar, target);   // h(t+1) visible everywhere before next step
  }
}

// logits[b][t][a] = hs[t+1][b][:] . Wd_t[a][:] + bd[a]
__global__ __launch_bounds__(256) void k_logits(
    const ushort* __restrict__ hs1, const ushort* __restrict__ Wdt,
    const float* __restrict__ bd, float* __restrict__ out) {
  int gid = blockIdx.x * 256 + threadIdx.x;
  int a = gid & 15, row = gid >> 4;   // row = t*64+b
  int t = row >> 6, b = row & 63;
  const uint4* hp = (const uint4*)(hs1 + (size_t)row * HH);
  const uint4* wp = (const uint4*)(Wdt + (size_t)a * HH);
  float sum = 0.f;
#pragma unroll 4
  for (int i = 0; i < HH / 8; ++i) {
    uint4 hv = hp[i], wv = wp[i];
    const uint* hu = (const uint*)&hv;
    const uint* wu = (const uint*)&wv;
#pragma unroll
    for (int j = 0; j < 4; ++j) {
      sum += bf2f((ushort)(hu[j] & 0xffff)) * bf2f((ushort)(wu[j] & 0xffff));
      sum += bf2f((ushort)(hu[j] >> 16)) * bf2f((ushort)(wu[j] >> 16));
    }
  }
  out[32768 + ((size_t)b * SS + t) * 16 + a] = sum + bd[a];
}

extern "C" void kernel_launch(void* const* d_in, const int* in_sizes, int n_in,
                              void* d_out, int out_size, void* d_ws, size_t ws_size,
                              hipStream_t stream) {
  const int*   x    = (const int*)d_in[0];
  const float* etok = (const float*)d_in[4];
  const float* epos = (const float*)d_in[5];
  const float* Wi   = (const float*)d_in[6];
  const float* Wh   = (const float*)d_in[7];
  const float* bh   = (const float*)d_in[8];
  const float* Wd   = (const float*)d_in[9];
  const float* bd   = (const float*)d_in[10];

  char* ws = (char*)d_ws;
  size_t off = 0;
  ushort* Wi_t = (ushort*)(ws + off); off += (size_t)G4 * HH * 2;            // 8 MB
  ushort* Wh_t = (ushort*)(ws + off); off += (size_t)G4 * HH * 2;            // 8 MB
  ushort* Wd_t = (ushort*)(ws + off); off += 65536;                          // 32 KB (padded)
  ushort* Ae   = (ushort*)(ws + off); off += (size_t)BB * SS * HH * 2;       // 64 MB
  ushort* xi   = (ushort*)(ws + off); off += (size_t)BB * SS * G4 * 2;       // 256 MB
  ushort* hs   = (ushort*)(ws + off); off += (size_t)(SS + 1) * BB * HH * 2; // 64.1 MB
  unsigned* bar = (unsigned*)(ws + off); off += 256;

  hipMemsetAsync(d_out, 0, (size_t)out_size * 4, stream);          // dummies = 0
  hipMemsetAsync(hs, 0, (size_t)BB * HH * 2, stream);              // h_0 = 0
  hipMemsetAsync(bar, 0, 256, stream);                             // barrier counter

  dim3 b256(256);
  k_transpose_cast<<<dim3(G4 / 32, HH / 32), b256, 0, stream>>>(Wi, Wi_t, HH, G4);
  k_transpose_cast<<<dim3(G4 / 32, HH / 32), b256, 0, stream>>>(Wh, Wh_t, HH, G4);
  k_transpose_cast<<<dim3(1, HH / 32), b256, 0, stream>>>(Wd, Wd_t, HH, 16);
  k_embed<<<BB * SS, b256, 0, stream>>>(x, etok, epos, Ae);
  k_gemm_xi<<<dim3(G4 / 128, BB * SS / 128), b256, 0, stream>>>(Ae, Wi_t, bh, xi, G4);
  k_recur<<<64, b256, 0, stream>>>(Wh_t, xi, hs, bar);
  k_logits<<<BB * SS * 16 / 256, b256, 0, stream>>>(hs + (size_t)BB * HH, Wd_t, bd,
                                                    (float*)d_out);
}

// Round 3
// 7446.073 us; speedup vs baseline: 1.5906x; 1.5064x over previous
//
#include <hip/hip_runtime.h>
#include <hip/hip_bf16.h>

#define BB 64
#define SS 512
#define HH 1024
#define G4 4096

using bf8_t = __attribute__((ext_vector_type(8))) short;   // 8 bf16 (4 VGPRs)
using f32x4 = __attribute__((ext_vector_type(4))) float;   // 4 fp32 acc

__device__ inline ushort f2bf(float f) {
  __hip_bfloat16 h = __float2bfloat16(f);
  return *reinterpret_cast<ushort*>(&h);
}
__device__ inline float bf2f(ushort u) {
  unsigned v = ((unsigned)u) << 16;
  return __uint_as_float(v);
}

// fp32 [R][C] -> bf16 [C][R]
__global__ __launch_bounds__(256) void k_transpose_cast(
    const float* __restrict__ in, ushort* __restrict__ out, int R, int C) {
  __shared__ float tile[32][33];
  int c0 = blockIdx.x * 32, r0 = blockIdx.y * 32;
  int tx = threadIdx.x & 31, ty = threadIdx.x >> 5;  // 32 x 8
  for (int i = ty; i < 32; i += 8) {
    int r = r0 + i, c = c0 + tx;
    tile[i][tx] = (r < R && c < C) ? in[(size_t)r * C + c] : 0.f;
  }
  __syncthreads();
  for (int i = ty; i < 32; i += 8) {
    int c = c0 + i, r = r0 + tx;
    if (c < C && r < R) out[(size_t)c * R + r] = f2bf(tile[tx][i]);
  }
}

// Ae[row = t*64+b][k] = embed_tok[x[b][t]][k] + embed_pos[t][k], bf16
__global__ __launch_bounds__(256) void k_embed(
    const int* __restrict__ x, const float* __restrict__ etok,
    const float* __restrict__ epos, ushort* __restrict__ Ae) {
  int row = blockIdx.x;
  int t = row >> 6, b = row & 63;
  int tok = x[b * SS + t];
  const float4* tp = (const float4*)(etok + (size_t)tok * HH);
  const float4* pp = (const float4*)(epos + (size_t)t * HH);
  int i = threadIdx.x;  // 256 threads * float4 = 1024
  float4 a = tp[i], p = pp[i];
  ushort4 r = make_ushort4(f2bf(a.x + p.x), f2bf(a.y + p.y),
                           f2bf(a.z + p.z), f2bf(a.w + p.w));
  ((ushort4*)(Ae + (size_t)row * HH))[i] = r;
}

// C[m][n] (bf16) = A[m][k] @ Bt[n][k]^T + bias[n].  M,N mult of 128, K=1024.
__global__ __launch_bounds__(256) void k_gemm_xi(
    const ushort* __restrict__ Ag, const ushort* __restrict__ Bt,
    const float* __restrict__ bias, ushort* __restrict__ Cout, int N) {
  __shared__ alignas(16) ushort As[128 * 40];   // rows padded 32->40 shorts
  __shared__ alignas(16) ushort Bs[128 * 40];
  const int m0 = blockIdx.y * 128, n0 = blockIdx.x * 128;
  const int tid = threadIdx.x;
  const int srow = tid >> 1, shalf = tid & 1;   // stage: 2 thr/row, 16 shorts each
  const int w = tid >> 6, lane = tid & 63;
  const int wm = w >> 1, wn = w & 1;            // 2x2 waves, 64x64 each
  const int lr = lane & 15, kq = lane >> 4;
  f32x4 acc[4][4] = {};
  for (int k0 = 0; k0 < HH; k0 += 32) {
    const uint4* ga = (const uint4*)(Ag + (size_t)(m0 + srow) * HH + k0 + shalf * 16);
    const uint4* gb = (const uint4*)(Bt + (size_t)(n0 + srow) * HH + k0 + shalf * 16);
    uint4 va0 = ga[0], va1 = ga[1];
    uint4 vb0 = gb[0], vb1 = gb[1];
    __syncthreads();
    *(uint4*)&As[srow * 40 + shalf * 16]     = va0;
    *(uint4*)&As[srow * 40 + shalf * 16 + 8] = va1;
    *(uint4*)&Bs[srow * 40 + shalf * 16]     = vb0;
    *(uint4*)&Bs[srow * 40 + shalf * 16 + 8] = vb1;
    __syncthreads();
    bf8_t fa[4], fb[4];
#pragma unroll
    for (int i = 0; i < 4; ++i) {
      fa[i] = *(const bf8_t*)&As[(wm * 64 + i * 16 + lr) * 40 + kq * 8];
      fb[i] = *(const bf8_t*)&Bs[(wn * 64 + i * 16 + lr) * 40 + kq * 8];
    }
#pragma unroll
    for (int mi = 0; mi < 4; ++mi)
#pragma unroll
      for (int ni = 0; ni < 4; ++ni)
        acc[mi][ni] = __builtin_amdgcn_mfma_f32_16x16x32_bf16(fa[mi], fb[ni], acc[mi][ni], 0, 0, 0);
  }
#pragma unroll
  for (int mi = 0; mi < 4; ++mi) {
    int grow = m0 + wm * 64 + mi * 16 + kq * 4;
#pragma unroll
    for (int ni = 0; ni < 4; ++ni) {
      int gcol = n0 + wn * 64 + ni * 16 + lr;
      float bv = bias[gcol];
#pragma unroll
      for (int r = 0; r < 4; ++r)
        Cout[(size_t)(grow + r) * N + gcol] = f2bf(acc[mi][ni][r] + bv);
    }
  }
}

// Persistent recurrence, batch-split into 4 independent groups of 16 rows.
// 256 WGs x 256 thr (1/CU). WG = (grp = bid>>6, mem = bid&63); owns h-cols
// [mem*16, mem*16+16) for batch rows [grp*16, grp*16+16). Wave g = gate g.
// Wh slice (64 gate-cols x 1024) lives in LDS (XOR-swizzled); c in registers.
// Per-group barrier: per-WG monotonic arrival slot (release store) + 64-lane
// acquire-poll. No atomic RMW, no explicit threadfence.
__global__ __launch_bounds__(256) void k_recur(
    const ushort* __restrict__ Wh_t,   // [4096][1024] bf16
    const ushort* __restrict__ xi,     // [S*64][4096] bf16 (bh folded in)
    ushort* __restrict__ hs,           // [(S+1)*64][1024] bf16, hs[0]=0
    unsigned* __restrict__ arrive) {   // [4][64] monotonic step counters
  __shared__ alignas(16) ushort Wlds[64 * 1024];   // 128 KiB
  __shared__ float zbuf[4][16][17];
  const int grp = blockIdx.x >> 6;      // batch group 0..3
  const int mem = blockIdx.x & 63;      // member in group
  const int n0 = mem * 16;
  const int brow0 = grp * 16;
  const int tid = threadIdx.x;
  unsigned* slot = arrive + grp * 64;

  // one-time stage of Wh slice, swizzled: unit u = row*128 + (k16 ^ (row&7))
  for (int s = tid; s < 64 * 128; s += 256) {
    int row = s >> 7, k16 = s & 127;
    int g = row >> 4, j = row & 15;
    uint4 v = *(const uint4*)(Wh_t + (size_t)(g * 1024 + n0 + j) * HH + k16 * 8);
    *(uint4*)&Wlds[(row * 128 + (k16 ^ (row & 7))) * 8] = v;
  }
  __syncthreads();

  const int w = tid >> 6, lane = tid & 63;
  const int lr = lane & 15, kq = lane >> 4;
  const int eb = tid >> 4, en = tid & 15;   // epilogue ownership: (batch, col)
  float cr = 0.f;                            // c-state

  for (int t = 0; t < SS; ++t) {
    const ushort* hprev = hs + (size_t)t * BB * HH;

    // xi values for epilogue — issue early
    const ushort* xr = xi + ((size_t)t * 64 + brow0 + eb) * G4 + n0 + en;
    ushort xv0 = xr[0], xv1 = xr[1024], xv2 = xr[2048], xv3 = xr[3072];

    // all 32 A-fragments upfront: 32 independent 16B loads in flight
    const ushort* hrow = hprev + (size_t)(brow0 + lr) * HH + kq * 8;
    bf8_t fa[32];
#pragma unroll
    for (int k = 0; k < 32; ++k) fa[k] = *(const bf8_t*)(hrow + k * 32);

    f32x4 acc0 = {}, acc1 = {};
#pragma unroll
    for (int k = 0; k < 32; k += 2) {
      bf8_t fb0 = *(const bf8_t*)&Wlds[((w * 16 + lr) * 128 + ((k * 4 + kq) ^ (lr & 7))) * 8];
      bf8_t fb1 = *(const bf8_t*)&Wlds[((w * 16 + lr) * 128 + ((k * 4 + 4 + kq) ^ (lr & 7))) * 8];
      acc0 = __builtin_amdgcn_mfma_f32_16x16x32_bf16(fa[k], fb0, acc0, 0, 0, 0);
      acc1 = __builtin_amdgcn_mfma_f32_16x16x32_bf16(fa[k + 1], fb1, acc1, 0, 0, 0);
    }
#pragma unroll
    for (int r = 0; r < 4; ++r)
      zbuf[w][kq * 4 + r][lr] = acc0[r] + acc1[r];
    __syncthreads();

    // epilogue: thread owns (b=eb, n=en)
    float zi = zbuf[0][eb][en] + bf2f(xv0);
    float zf = zbuf[1][eb][en] + bf2f(xv1);
    float zg = zbuf[2][eb][en] + bf2f(xv2);
    float zo = zbuf[3][eb][en] + bf2f(xv3);
    float si = 1.f / (1.f + __expf(-zi));
    float sf = 1.f / (1.f + __expf(-zf));
    float tg = tanhf(zg);
    float so = 1.f / (1.f + __expf(-zo));
    float c = sf * cr + si * tg;
    cr = c;
    hs[(size_t)(t + 1) * BB * HH + (size_t)(brow0 + eb) * HH + n0 + en] =
        f2bf(so * tanhf(c));
    __syncthreads();  // all h-stores issued + vmcnt drained (also zbuf reuse)

    // arrive: release store pushes our h (and prior stores) to device scope
    if (tid == 0)
      __hip_atomic_store(slot + mem, (unsigned)(t + 1), __ATOMIC_RELEASE,
                         __HIP_MEMORY_SCOPE_AGENT);
    // poll: lane l watches member l's slot; acquire gives us their h
    if (tid < 64) {
      while (__hip_atomic_load(slot + tid, __ATOMIC_ACQUIRE,
                               __HIP_MEMORY_SCOPE_AGENT) < (unsigned)(t + 1))
        __builtin_amdgcn_s_sleep(1);
    }
    __syncthreads();
  }
}

// logits[b][t][a] = hs[t+1][b][:] . Wd_t[a][:] + bd[a]
__global__ __launch_bounds__(256) void k_logits(
    const ushort* __restrict__ hs1, const ushort* __restrict__ Wdt,
    const float* __restrict__ bd, float* __restrict__ out) {
  int gid = blockIdx.x * 256 + threadIdx.x;
  int a = gid & 15, row = gid >> 4;   // row = t*64+b
  int t = row >> 6, b = row & 63;
  const uint4* hp = (const uint4*)(hs1 + (size_t)row * HH);
  const uint4* wp = (const uint4*)(Wdt + (size_t)a * HH);
  float sum = 0.f;
#pragma unroll 4
  for (int i = 0; i < HH / 8; ++i) {
    uint4 hv = hp[i], wv = wp[i];
    const uint* hu = (const uint*)&hv;
    const uint* wu = (const uint*)&wv;
#pragma unroll
    for (int j = 0; j < 4; ++j) {
      sum += bf2f((ushort)(hu[j] & 0xffff)) * bf2f((ushort)(wu[j] & 0xffff));
      sum += bf2f((ushort)(hu[j] >> 16)) * bf2f((ushort)(wu[j] >> 16));
    }
  }
  out[32768 + ((size_t)b * SS + t) * 16 + a] = sum + bd[a];
}

extern "C" void kernel_launch(void* const* d_in, const int* in_sizes, int n_in,
                              void* d_out, int out_size, void* d_ws, size_t ws_size,
                              hipStream_t stream) {
  const int*   x    = (const int*)d_in[0];
  const float* etok = (const float*)d_in[4];
  const float* epos = (const float*)d_in[5];
  const float* Wi   = (const float*)d_in[6];
  const float* Wh   = (const float*)d_in[7];
  const float* bh   = (const float*)d_in[8];
  const float* Wd   = (const float*)d_in[9];
  const float* bd   = (const float*)d_in[10];

  char* ws = (char*)d_ws;
  size_t off = 0;
  ushort* Wi_t = (ushort*)(ws + off); off += (size_t)G4 * HH * 2;            // 8 MB
  ushort* Wh_t = (ushort*)(ws + off); off += (size_t)G4 * HH * 2;            // 8 MB
  ushort* Wd_t = (ushort*)(ws + off); off += 65536;                          // 32 KB (padded)
  ushort* Ae   = (ushort*)(ws + off); off += (size_t)BB * SS * HH * 2;       // 64 MB
  ushort* xi   = (ushort*)(ws + off); off += (size_t)BB * SS * G4 * 2;       // 256 MB
  ushort* hs   = (ushort*)(ws + off); off += (size_t)(SS + 1) * BB * HH * 2; // 64.1 MB
  unsigned* arrive = (unsigned*)(ws + off); off += 4096;

  hipMemsetAsync(d_out, 0, (size_t)out_size * 4, stream);          // dummies = 0
  hipMemsetAsync(hs, 0, (size_t)BB * HH * 2, stream);              // h_0 = 0
  hipMemsetAsync(arrive, 0, 4096, stream);                         // barrier slots

  dim3 b256(256);
  k_transpose_cast<<<dim3(G4 / 32, HH / 32), b256, 0, stream>>>(Wi, Wi_t, HH, G4);
  k_transpose_cast<<<dim3(G4 / 32, HH / 32), b256, 0, stream>>>(Wh, Wh_t, HH, G4);
  k_transpose_cast<<<dim3(1, HH / 32), b256, 0, stream>>>(Wd, Wd_t, HH, 16);
  k_embed<<<BB * SS, b256, 0, stream>>>(x, etok, epos, Ae);
  k_gemm_xi<<<dim3(G4 / 128, BB * SS / 128), b256, 0, stream>>>(Ae, Wi_t, bh, xi, G4);
  k_recur<<<256, b256, 0, stream>>>(Wh_t, xi, hs, arrive);
  k_logits<<<BB * SS * 16 / 256, b256, 0, stream>>>(hs + (size_t)BB * HH, Wd_t, bd,
                                                    (float*)d_out);
}